// Round 12
// baseline (272.669 us; speedup 1.0000x reference)
//
#include <hip/hip_runtime.h>

// Problem: B,H,W,D = 64,32,32,64 ; K=1024 ; N = 65536
#define NPTS   65536
#define DDIM   64
#define KCODES 1024
#define QOUT_ELEMS (NPTS * DDIM)

typedef _Float16 half8    __attribute__((ext_vector_type(8)));
typedef float    floatx16 __attribute__((ext_vector_type(16)));
typedef unsigned int uint;

#define AS1 __attribute__((address_space(1)))
#define AS3 __attribute__((address_space(3)))

// ws: ehp [0,128K) chunk-major f16 | elp [128K,256K) | e2 fp32 [256K,260K)
// diag scratch: [1MiB, 1.5MiB)
#define WS_EHP   0
#define WS_ELP   (128*1024)
#define WS_E2    (256*1024)

static __device__ __forceinline__ void gl_lds16(const void* g, void* l) {
    __builtin_amdgcn_global_load_lds((const AS1 uint*)g, (AS3 uint*)l, 16, 0, 0);
}

// ---------------------------------------------------------------------------
// Prep: one wave per code. fp16 hi/lo split, CHUNK-MAJOR tiles:
// tile T=k>>5, chunk j=d>>3, code-in-tile c=k&31:
//   byte off = T*4096 + j*512 + c*16 + (d&7)*2
// e2 (||e||^2) stored as plain fp32 (added post-MFMA, exact).
// ---------------------------------------------------------------------------
__global__ void eprep_kernel(const float* __restrict__ emb, char* __restrict__ ws) {
    const int tid = threadIdx.x;
    const int w = tid >> 6, d = tid & 63;
    const int k = blockIdx.x * 4 + w;
    float v = emb[(size_t)k * DDIM + d];
    _Float16 h = (_Float16)v;
    _Float16 l = (_Float16)(v - (float)h);
    size_t off = (size_t)(k >> 5) * 4096 + (size_t)(d >> 3) * 512
               + (size_t)(k & 31) * 16 + (size_t)(d & 7) * 2;
    *(_Float16*)(ws + WS_EHP + off) = h;
    *(_Float16*)(ws + WS_ELP + off) = l;
    float s = v * v;
    #pragma unroll
    for (int m = 1; m < 64; m <<= 1) s += __shfl_xor(s, m, 64);
    if (d == 0) ((float*)(ws + WS_E2))[k] = s;
}

#define MFMA(A,B,C) __builtin_amdgcn_mfma_f32_32x32x16_f16(A,B,C,0,0,0)

// ===========================================================================
// DIAGNOSTIC (this round): pure-compute floor of R6's COMP body.
// Frags loaded ONCE from global; loop = 8 reps x 32 tiles of {2x6-deep MFMA
// chains + argmin}, NO LDS traffic, NO barriers. FUZZ = bit_cast -> empty
// asm "+v" -> bit_cast per frag per iteration: zero instructions, but marks
// the chain inputs modified so the compiler cannot hoist/CSE the identical
// MFMAs across iterations (rule #17; R7-V2 was likely hoisted).
// Decision (pre-committed): dur/8 >= ~21us -> chains are dep-latency-bound,
// structural floor confirmed; dur/8 <= ~16us -> memory path is the lever.
// ===========================================================================
__global__ __launch_bounds__(256, 2) void vq_diag2(
    const float* __restrict__ z,
    const char* __restrict__ ws_c,
    float* __restrict__ scratch)
{
    const int tid  = threadIdx.x;
    const int lane = tid & 63;
    const int w    = __builtin_amdgcn_readfirstlane(tid >> 6);
    const int col  = lane & 31;
    const int sel8 = lane >> 5;
    const int pgrp = blockIdx.x;

    __shared__ char  ebuf[4][8192];   // kept allocated: occupancy parity
    __shared__ float lds_e2[1024];

    // A fragments (same env as real kernel)
    const int pt = pgrp * 128 + w * 32 + col;
    half8 ah[4], al[4];
    {
        const float* zrow = z + (size_t)pt * DDIM + sel8 * 8;
        #pragma unroll
        for (int ks = 0; ks < 4; ++ks) {
            float4 u0 = *(const float4*)(zrow + ks * 16);
            float4 u1 = *(const float4*)(zrow + ks * 16 + 4);
            float tv[8] = {u0.x, u0.y, u0.z, u0.w, u1.x, u1.y, u1.z, u1.w};
            #pragma unroll
            for (int j = 0; j < 8; ++j) {
                float a = -2.0f * tv[j];
                _Float16 hh = (_Float16)a;
                ah[ks][j] = hh;
                al[ks][j] = (_Float16)(a - (float)hh);
            }
        }
    }

    const floatx16 zeroC = {};
    float best[16];
    int   bt[16];
    #pragma unroll
    for (int r = 0; r < 16; ++r) { best[r] = 3.4e38f; bt[r] = 0; }

    // one-time direct frag load (tile 0 of ws), then pure compute
    const int myoff = sel8 * 512 + col * 16;
    half8 bh[4], bl[4];
    {
        const char* _b = ws_c + myoff;
        #pragma unroll
        for (int ks = 0; ks < 4; ++ks) {
            bh[ks] = *(const half8*)(_b + ks * 1024);
            bl[ks] = *(const half8*)(_b + WS_ELP + ks * 1024);
        }
    }
    float e2v = ((const float*)(ws_c + WS_E2))[col];

#define FUZZ(V) do {                                                          \
    uint4 _t = __builtin_bit_cast(uint4, V);                                  \
    asm volatile("" : "+v"(_t.x), "+v"(_t.y), "+v"(_t.z), "+v"(_t.w));        \
    V = __builtin_bit_cast(half8, _t);                                        \
} while (0)

    #pragma unroll 1
    for (int rep = 0; rep < 8; ++rep) {
        #pragma unroll 1
        for (int t = 0; t < 32; ++t) {
            FUZZ(bh[0]); FUZZ(bh[1]); FUZZ(bh[2]); FUZZ(bh[3]);
            FUZZ(bl[0]); FUZZ(bl[1]); FUZZ(bl[2]); FUZZ(bl[3]);
            asm volatile("" : "+v"(e2v));

            __builtin_amdgcn_s_setprio(1);
            floatx16 c0 = MFMA(ah[0], bh[0], zeroC);
            floatx16 c1 = MFMA(ah[0], bl[0], zeroC);
            c0 = MFMA(ah[1], bh[1], c0);  c1 = MFMA(ah[1], bl[1], c1);
            c0 = MFMA(ah[2], bh[2], c0);  c1 = MFMA(ah[2], bl[2], c1);
            c0 = MFMA(ah[3], bh[3], c0);  c1 = MFMA(ah[3], bl[3], c1);
            c0 = MFMA(al[0], bh[0], c0);  c1 = MFMA(al[2], bh[2], c1);
            c0 = MFMA(al[1], bh[1], c0);  c1 = MFMA(al[3], bh[3], c1);
            __builtin_amdgcn_s_setprio(0);

            #pragma unroll
            for (int r = 0; r < 16; ++r) {
                float d = (c0[r] + c1[r]) + e2v;
                bool c = d < best[r];
                best[r] = c ? d : best[r];
                bt[r]   = c ? t : bt[r];
            }
        }
    }
#undef FUZZ

    // butterfly + sink everything (no DCE)
    int code[16];
    #pragma unroll
    for (int r = 0; r < 16; ++r) code[r] = bt[r] * 32 + col;
    #pragma unroll
    for (int m = 1; m < 32; m <<= 1) {
        #pragma unroll
        for (int r = 0; r < 16; ++r) {
            float ov = __shfl_xor(best[r], m, 64);
            int   oc = __shfl_xor(code[r], m, 64);
            bool c = (ov < best[r]) || (ov == best[r] && oc < code[r]);
            best[r] = c ? ov : best[r];
            code[r] = c ? oc : code[r];
        }
    }
    float accv = 0.0f;
    #pragma unroll
    for (int r = 0; r < 16; ++r) accv += best[r] + (float)code[r];
    scratch[pgrp * 256 + tid] = accv;
    if (pgrp == 0x7fffffff)   // never true: keeps LDS allocated
        scratch[0] = (float)ebuf[0][0] + lds_e2[0];
}

// ===========================================================================
// REAL kernel: byte-identical to Round-6 (best verified, ~40us, absmax 0).
// ===========================================================================
__global__ __launch_bounds__(256, 2) void vq_kernel(
    const float* __restrict__ z,
    const char* __restrict__ ws_c,
    const float* __restrict__ emb,
    float* __restrict__ out)
{
    const int tid  = threadIdx.x;
    const int lane = tid & 63;
    const int w    = __builtin_amdgcn_readfirstlane(tid >> 6);
    const int col  = lane & 31;
    const int sel8 = lane >> 5;
    const int pgrp = blockIdx.x;

    __shared__ char  ebuf[4][8192];   // ring: [buf][eh 4KB | el 4KB] = 32KB
    __shared__ float lds_e2[1024];    // 4KB fp32 ||e||^2, all codes
    __shared__ int   s_final[128];

    const int pt = pgrp * 128 + w * 32 + col;
    half8 ah[4], al[4];
    {
        const float* zrow = z + (size_t)pt * DDIM + sel8 * 8;
        #pragma unroll
        for (int ks = 0; ks < 4; ++ks) {
            float4 u0 = *(const float4*)(zrow + ks * 16);
            float4 u1 = *(const float4*)(zrow + ks * 16 + 4);
            float tv[8] = {u0.x, u0.y, u0.z, u0.w, u1.x, u1.y, u1.z, u1.w};
            #pragma unroll
            for (int j = 0; j < 8; ++j) {
                float a = -2.0f * tv[j];
                _Float16 hh = (_Float16)a;
                ah[ks][j] = hh;
                al[ks][j] = (_Float16)(a - (float)hh);
            }
        }
    }
    // drain A-frag vmem so loop vmcnt accounting sees ONLY gl_lds ops
    asm volatile("s_waitcnt vmcnt(0)" ::: "memory");
    __builtin_amdgcn_sched_barrier(0);

    const floatx16 zeroC = {};
    float best[16];
    int   bt[16];
    #pragma unroll
    for (int r = 0; r < 16; ++r) { best[r] = 3.4e38f; bt[r] = 0; }

    // wave w stages 2KB/tile: operand = w>>1 (0=eh,1=el), half = w&1
    const int opnd = w >> 1, hsel = w & 1;
    const char* gsrc = ws_c + (opnd ? WS_ELP : WS_EHP) + hsel * 2048 + lane * 16;
    char* lbase = &ebuf[0][0] + opnd * 4096 + hsel * 2048;

#define STAGE(BUF, T) do {                                                    \
    const char* _s = gsrc + (size_t)(T) * 4096;                               \
    char* _d = lbase + (BUF) * 8192;                                          \
    gl_lds16(_s,        _d);                                                  \
    gl_lds16(_s + 1024, _d + 1024);                                           \
} while (0)

    const int myoff = sel8 * 512 + col * 16;   // chunk-major frag base in tile

#define READF(BUF, T, BH, BL, E2) do {                                        \
    const char* _b = &ebuf[BUF][0] + myoff;                                   \
    _Pragma("unroll")                                                         \
    for (int ks = 0; ks < 4; ++ks) {                                          \
        BH[ks] = *(const half8*)(_b + ks * 1024);                             \
        BL[ks] = *(const half8*)(_b + 4096 + ks * 1024);                      \
    }                                                                         \
    E2 = lds_e2[(T) * 32 + col];                                              \
} while (0)

#define COMP(T, BH, BL, E2) do {                                              \
    __builtin_amdgcn_s_setprio(1);                                            \
    floatx16 c0 = MFMA(ah[0], BH[0], zeroC);                                  \
    floatx16 c1 = MFMA(ah[0], BL[0], zeroC);                                  \
    c0 = MFMA(ah[1], BH[1], c0);  c1 = MFMA(ah[1], BL[1], c1);                \
    c0 = MFMA(ah[2], BH[2], c0);  c1 = MFMA(ah[2], BL[2], c1);                \
    c0 = MFMA(ah[3], BH[3], c0);  c1 = MFMA(ah[3], BL[3], c1);                \
    c0 = MFMA(al[0], BH[0], c0);  c1 = MFMA(al[2], BH[2], c1);                \
    c0 = MFMA(al[1], BH[1], c0);  c1 = MFMA(al[3], BH[3], c1);                \
    __builtin_amdgcn_s_setprio(0);                                            \
    _Pragma("unroll")                                                         \
    for (int r = 0; r < 16; ++r) {                                            \
        float d = (c0[r] + c1[r]) + (E2);                                     \
        bool c = d < best[r];          /* strict <: earliest tile wins */     \
        best[r] = c ? d   : best[r];                                          \
        bt[r]   = c ? (T) : bt[r];                                            \
    }                                                                         \
} while (0)

#define WAITBAR(N) do {                                                       \
    asm volatile("s_waitcnt vmcnt(" #N ") lgkmcnt(0)" ::: "memory");          \
    __builtin_amdgcn_sched_barrier(0);                                        \
    __builtin_amdgcn_s_barrier();                                             \
    __builtin_amdgcn_sched_barrier(0);                                        \
} while (0)

    half8 bhA[4], blA[4], bhB[4], blB[4];
    float e2A, e2B;

    // -------- prologue: e2 + tiles 0..2 in flight (7 ops) --------
    gl_lds16(ws_c + WS_E2 + w * 1024 + lane * 16, (char*)lds_e2 + w * 1024);
    STAGE(0, 0);
    STAGE(1, 1);
    STAGE(2, 2);
    WAITBAR(4);                 // retire e2 + tile0 (3 oldest ops)
    READF(0, 0, bhA, blA, e2A);
    STAGE(3, 3);                // in flight: tiles 1,2,3 = 6 ops

    // -------- main loop: tiles 0..27, always 3 tiles ahead --------
    #pragma unroll 1
    for (int t = 0; t < 28; t += 2) {
        WAITBAR(4);                              // retire tile t+1
        READF((t + 1) & 3, t + 1, bhB, blB, e2B);
        STAGE((t + 4) & 3, t + 4);
        COMP(t, bhA, blA, e2A);

        WAITBAR(4);                              // retire tile t+2
        READF((t + 2) & 3, t + 2, bhA, blA, e2A);
        STAGE((t + 5) & 3, t + 5);
        COMP(t + 1, bhB, blB, e2B);
    }

    // -------- tail: tiles 28..31, draining the ring --------
    WAITBAR(4);                 // in flight {29,30,31}: retire 29
    READF(29 & 3, 29, bhB, blB, e2B);
    COMP(28, bhA, blA, e2A);

    WAITBAR(2);                 // in flight {30,31}: retire 30
    READF(30 & 3, 30, bhA, blA, e2A);
    COMP(29, bhB, blB, e2B);

    WAITBAR(0);                 // in flight {31}: retire 31
    READF(31 & 3, 31, bhB, blB, e2B);
    COMP(30, bhA, blA, e2A);

    COMP(31, bhB, blB, e2B);
#undef STAGE
#undef READF
#undef COMP
#undef WAITBAR

    int code[16];
    #pragma unroll
    for (int r = 0; r < 16; ++r) code[r] = bt[r] * 32 + col;
    #pragma unroll
    for (int m = 1; m < 32; m <<= 1) {
        #pragma unroll
        for (int r = 0; r < 16; ++r) {
            float ov = __shfl_xor(best[r], m, 64);
            int   oc = __shfl_xor(code[r], m, 64);
            bool c = (ov < best[r]) || (ov == best[r] && oc < code[r]);
            best[r] = c ? ov : best[r];
            code[r] = c ? oc : code[r];
        }
    }
    if (col == 0) {   // lanes 0 and 32: 16 rows each
        #pragma unroll
        for (int r = 0; r < 16; ++r) {
            int row = (r & 3) + 8 * (r >> 2) + 4 * sel8;
            s_final[w * 32 + row] = code[r];
        }
    }
    __syncthreads();

    if (tid < 128)
        out[QOUT_ELEMS + (size_t)pgrp * 128 + tid] = (float)s_final[tid];
    float4* outq = (float4*)out;
    const float4* emb4 = (const float4*)emb;
    #pragma unroll
    for (int it = 0; it < 8; ++it) {
        int f  = it * 256 + tid;
        int p  = f >> 4;
        int d4 = f & 15;
        int ks = s_final[p];
        outq[((size_t)pgrp * 128 + p) * (DDIM / 4) + d4] =
            emb4[(size_t)ks * (DDIM / 4) + d4];
    }
}

extern "C" void kernel_launch(void* const* d_in, const int* in_sizes, int n_in,
                              void* d_out, int out_size, void* d_ws, size_t ws_size,
                              hipStream_t stream) {
    const float* z   = (const float*)d_in[0];
    const float* emb = (const float*)d_in[1];
    float* out = (float*)d_out;
    char* ws = (char*)d_ws;

    eprep_kernel<<<KCODES / 4, 256, 0, stream>>>(emb, ws);

    // diagnostic (this round only): compute-only floor, CSE-proofed
    float* sc = (float*)(ws + (1 << 20));
    vq_diag2<<<NPTS / 128, 256, 0, stream>>>(z, ws, sc);

    // real kernel (unchanged Round-6 best)
    vq_kernel<<<NPTS / 128, 256, 0, stream>>>(z, ws, emb, out);
}

// Round 13
// 107.110 us; speedup vs baseline: 2.5457x; 2.5457x over previous
//
#include <hip/hip_runtime.h>

// Problem: B,H,W,D = 64,32,32,64 ; K=1024 ; N = 65536
#define NPTS   65536
#define DDIM   64
#define KCODES 1024
#define QOUT_ELEMS (NPTS * DDIM)

typedef _Float16 half8    __attribute__((ext_vector_type(8)));
typedef float    floatx16 __attribute__((ext_vector_type(16)));
typedef unsigned int uint;

#define AS1 __attribute__((address_space(1)))
#define AS3 __attribute__((address_space(3)))

// ws: ehp [0,128K) chunk-major f16 | elp [128K,256K) | e2 fp32 [256K,260K)
#define WS_EHP   0
#define WS_ELP   (128*1024)
#define WS_E2    (256*1024)

static __device__ __forceinline__ void gl_lds16(const void* g, void* l) {
    __builtin_amdgcn_global_load_lds((const AS1 uint*)g, (AS3 uint*)l, 16, 0, 0);
}

// ---------------------------------------------------------------------------
// Prep: one wave per code. fp16 hi/lo split, CHUNK-MAJOR tiles:
// tile T=k>>5, chunk j=d>>3, code-in-tile c=k&31:
//   byte off = T*4096 + j*512 + c*16 + (d&7)*2
// e2 (||e||^2) stored as plain fp32 (added post-MFMA, exact).
// ---------------------------------------------------------------------------
__global__ void eprep_kernel(const float* __restrict__ emb, char* __restrict__ ws) {
    const int tid = threadIdx.x;
    const int w = tid >> 6, d = tid & 63;
    const int k = blockIdx.x * 4 + w;
    float v = emb[(size_t)k * DDIM + d];
    _Float16 h = (_Float16)v;
    _Float16 l = (_Float16)(v - (float)h);
    size_t off = (size_t)(k >> 5) * 4096 + (size_t)(d >> 3) * 512
               + (size_t)(k & 31) * 16 + (size_t)(d & 7) * 2;
    *(_Float16*)(ws + WS_EHP + off) = h;
    *(_Float16*)(ws + WS_ELP + off) = l;
    float s = v * v;
    #pragma unroll
    for (int m = 1; m < 64; m <<= 1) s += __shfl_xor(s, m, 64);
    if (d == 0) ((float*)(ws + WS_E2))[k] = s;
}

// ---------------------------------------------------------------------------
// Main: grid 1024, block 256 = 4 waves, 64 points per block.
// Round-13: REGISTER-FEASIBLE 4 waves/SIMD. Evidence chain:
//  - diag2 (R12): compute body alone = 22.3us at 2 waves/SIMD unsynced,
//    MfmaUtil 60.7 / VALUBusy 70.7 -> neither pipe saturated; one wave's
//    chain-dep and argmin-VALU alternate with only 2 waves to anti-phase.
//    MFMA-pipe floor = 10.9us -> occupancy is the remaining compute lever.
//  - R2/R9 "TLP null" results were BOTH register-polluted (R2: VGPR 64 +
//    WRITE_SIZE 20.7MB>16.6 = silent spill; R9: 330MB). A clean 4-wave/SIMD
//    kernel never ran.
// Fixes to make it fit 128 regs (bounds(256,4)): SINGLE 12-MFMA chain
// (acc 16 regs; d = acc[r]+e2 -> also -16 VALU/tile) and SINGLE B-regset
// (READF(t)->COMP(t); ~200cy lgkm exposure covered by 4-way TLP).
// Ledger: ah/al 32 + bh/bl 32 + acc 16 + best/bt 32 + addr ~8 = ~120 < 128.
// K-SPLIT: waves {0,1} -> tiles 0..15, {2,3} -> 16..31 (same 64 points);
// 4 blocks/CU (LDS 37.4KB), per-SIMD waves come from 4 independent blocks.
// Ring-2 per pair; STAGE(t+1) issued before COMP(t), waited after (~700cy
// cover); raw s_barrier (no __syncthreads vmcnt-drain semantics).
// Spill tripwire: WRITE_SIZE > 25MB invalidates the round.
//
// MFMA 32x32x16 f16 layouts (verified, absmax 0):
//   A[m][k]: m=lane&31, k=(lane>>5)*8+j ; B same with n=lane&31 ;
//   C/D: col=lane&31, row=(r&3)+8*(r>>2)+4*(lane>>5)
// ---------------------------------------------------------------------------
#define MFMA(A,B,C) __builtin_amdgcn_mfma_f32_32x32x16_f16(A,B,C,0,0,0)

__global__ __launch_bounds__(256, 4) void vq_kernel(
    const float* __restrict__ z,
    const char* __restrict__ ws_c,
    const float* __restrict__ emb,
    float* __restrict__ out)
{
    const int tid   = threadIdx.x;
    const int lane  = tid & 63;
    const int w     = __builtin_amdgcn_readfirstlane(tid >> 6);
    const int col   = lane & 31;
    const int sel8  = lane >> 5;
    const int pgrp  = blockIdx.x;      // 64 points per block
    const int pair  = w >> 1;          // K-half: 0 -> tiles 0..15, 1 -> 16..31
    const int phalf = w & 1;           // point sub-group AND staging operand
    const int tbase = pair * 16;

    __shared__ char  ebuf[2][2][8192]; // [pair][slot][eh 4KB | el 4KB] = 32KB
    __shared__ float lds_e2[1024];     // 4KB fp32 ||e||^2, all codes
    __shared__ float sbest[2][64];
    __shared__ int   scode[2][64];
    __shared__ int   s_final[64];

    // ---- A fragments: a = -2 z[pt], hi/lo fp16 ----
    const int pt = pgrp * 64 + phalf * 32 + col;
    half8 ah[4], al[4];
    {
        const float* zrow = z + (size_t)pt * DDIM + sel8 * 8;
        #pragma unroll
        for (int ks = 0; ks < 4; ++ks) {
            float4 u0 = *(const float4*)(zrow + ks * 16);
            float4 u1 = *(const float4*)(zrow + ks * 16 + 4);
            float tv[8] = {u0.x, u0.y, u0.z, u0.w, u1.x, u1.y, u1.z, u1.w};
            #pragma unroll
            for (int j = 0; j < 8; ++j) {
                float a = -2.0f * tv[j];
                _Float16 hh = (_Float16)a;
                ah[ks][j] = hh;
                al[ks][j] = (_Float16)(a - (float)hh);
            }
        }
    }
    // drain A-frag vmem so loop vmcnt accounting sees ONLY gl_lds ops
    asm volatile("s_waitcnt vmcnt(0)" ::: "memory");
    __builtin_amdgcn_sched_barrier(0);

    const floatx16 zeroC = {};
    float best[16];
    int   bt[16];
    #pragma unroll
    for (int r = 0; r < 16; ++r) { best[r] = 3.4e38f; bt[r] = 0; }

    // wave (pair,phalf) stages operand phalf (0=eh,1=el) 4KB/tile for ITS pair
    const char* gsrc = ws_c + (phalf ? WS_ELP : WS_EHP) + lane * 16;
    char* lbase = &ebuf[pair][0][0] + phalf * 4096 + lane * 16;

#define STAGE(SLOT, T) do {                                                   \
    const char* _s = gsrc + (size_t)(tbase + (T)) * 4096;                     \
    char* _d = lbase + (SLOT) * 8192;                                         \
    gl_lds16(_s,        _d);                                                  \
    gl_lds16(_s + 1024, _d + 1024);                                           \
    gl_lds16(_s + 2048, _d + 2048);                                           \
    gl_lds16(_s + 3072, _d + 3072);                                           \
} while (0)

    const int myoff = sel8 * 512 + col * 16;   // chunk-major frag base in tile

    // single regset (fits 128-reg budget for 4 waves/EU)
    half8 bh[4], bl[4];
    float e2v;

#define READF(SLOT, T) do {                                                   \
    const char* _b = &ebuf[pair][SLOT][0] + myoff;                            \
    _Pragma("unroll")                                                         \
    for (int ks = 0; ks < 4; ++ks) {                                          \
        bh[ks] = *(const half8*)(_b + ks * 1024);                             \
        bl[ks] = *(const half8*)(_b + 4096 + ks * 1024);                      \
    }                                                                         \
    e2v = lds_e2[(tbase + (T)) * 32 + col];                                   \
} while (0)

// SINGLE 12-deep chain -> 16 acc regs; d = acc[r] + e2 (one add per row)
#define COMP(T) do {                                                          \
    __builtin_amdgcn_s_setprio(1);                                            \
    floatx16 acc = MFMA(ah[0], bh[0], zeroC);                                 \
    acc = MFMA(ah[1], bh[1], acc);                                            \
    acc = MFMA(ah[2], bh[2], acc);                                            \
    acc = MFMA(ah[3], bh[3], acc);                                            \
    acc = MFMA(ah[0], bl[0], acc);                                            \
    acc = MFMA(ah[1], bl[1], acc);                                            \
    acc = MFMA(ah[2], bl[2], acc);                                            \
    acc = MFMA(ah[3], bl[3], acc);                                            \
    acc = MFMA(al[0], bh[0], acc);                                            \
    acc = MFMA(al[1], bh[1], acc);                                            \
    acc = MFMA(al[2], bh[2], acc);                                            \
    acc = MFMA(al[3], bh[3], acc);                                            \
    __builtin_amdgcn_s_setprio(0);                                            \
    _Pragma("unroll")                                                         \
    for (int r = 0; r < 16; ++r) {                                            \
        float d = acc[r] + e2v;                                               \
        bool c = d < best[r];          /* strict <: earliest tile wins */     \
        best[r] = c ? d          : best[r];                                   \
        bt[r]   = c ? (tbase+(T)) : bt[r];                                    \
    }                                                                         \
} while (0)

// vmcnt(0): the waited STAGE was issued a full COMP (~700cy) earlier.
// lgkmcnt(0): own ds_reads done before anyone overwrites that slot.
#define WAITBAR do {                                                          \
    asm volatile("s_waitcnt vmcnt(0) lgkmcnt(0)" ::: "memory");               \
    __builtin_amdgcn_sched_barrier(0);                                        \
    __builtin_amdgcn_s_barrier();                                             \
    __builtin_amdgcn_sched_barrier(0);                                        \
} while (0)

    // -------- prologue: e2 + tile 0 staged --------
    gl_lds16(ws_c + WS_E2 + w * 1024 + lane * 16, (char*)lds_e2 + w * 1024);
    STAGE(0, 0);
    WAITBAR;

    // -------- main loop: 16 tiles --------
    #pragma unroll 1
    for (int t = 0; t < 16; ++t) {
        READF(t & 1, t);                       // ds_reads from slot t&1
        if (t < 15) STAGE((t + 1) & 1, t + 1); // 4 gl_lds into other slot
        COMP(t);                               // compiler inserts lgkm waits
        if (t < 15) WAITBAR;                   // stage landed; reads drained
    }
#undef STAGE
#undef READF
#undef COMP
#undef WAITBAR

    // butterfly argmin across the 32 columns (codes already absolute)
    int code[16];
    #pragma unroll
    for (int r = 0; r < 16; ++r) code[r] = bt[r] * 32 + col;
    #pragma unroll
    for (int m = 1; m < 32; m <<= 1) {
        #pragma unroll
        for (int r = 0; r < 16; ++r) {
            float ov = __shfl_xor(best[r], m, 64);
            int   oc = __shfl_xor(code[r], m, 64);
            bool c = (ov < best[r]) || (ov == best[r] && oc < code[r]);
            best[r] = c ? ov : best[r];
            code[r] = c ? oc : code[r];
        }
    }
    if (col == 0) {    // lanes 0 and 32: 16 rows each
        #pragma unroll
        for (int r = 0; r < 16; ++r) {
            int row = (r & 3) + 8 * (r >> 2) + 4 * sel8;
            sbest[pair][phalf * 32 + row] = best[r];
            scode[pair][phalf * 32 + row] = code[r];
        }
    }
    __syncthreads();

    // combine the two K-halves: strict < (half-0 codes are all smaller)
    if (tid < 64) {
        float d0 = sbest[0][tid], d1 = sbest[1][tid];
        s_final[tid] = (d1 < d0) ? scode[1][tid] : scode[0][tid];
    }
    __syncthreads();

    // indices (coalesced) + quantized gather: 64 pts x 16 float4
    if (tid < 64)
        out[QOUT_ELEMS + (size_t)pgrp * 64 + tid] = (float)s_final[tid];
    float4* outq = (float4*)out;
    const float4* emb4 = (const float4*)emb;
    #pragma unroll
    for (int it = 0; it < 4; ++it) {
        int f  = it * 256 + tid;
        int p  = f >> 4;
        int d4 = f & 15;
        int ks = s_final[p];
        outq[((size_t)pgrp * 64 + p) * (DDIM / 4) + d4] =
            emb4[(size_t)ks * (DDIM / 4) + d4];
    }
}

extern "C" void kernel_launch(void* const* d_in, const int* in_sizes, int n_in,
                              void* d_out, int out_size, void* d_ws, size_t ws_size,
                              hipStream_t stream) {
    const float* z   = (const float*)d_in[0];
    const float* emb = (const float*)d_in[1];
    float* out = (float*)d_out;
    char* ws = (char*)d_ws;

    eprep_kernel<<<KCODES / 4, 256, 0, stream>>>(emb, ws);
    vq_kernel<<<NPTS / 64, 256, 0, stream>>>(z, ws, emb, out);
}

// Round 14
// 103.371 us; speedup vs baseline: 2.6378x; 1.0362x over previous
//
#include <hip/hip_runtime.h>

// Problem: B,H,W,D = 64,32,32,64 ; K=1024 ; N = 65536
#define NPTS   65536
#define DDIM   64
#define KCODES 1024
#define QOUT_ELEMS (NPTS * DDIM)

typedef _Float16 half8    __attribute__((ext_vector_type(8)));
typedef float    floatx16 __attribute__((ext_vector_type(16)));
typedef unsigned int uint;

// ws: ehp [0,128K) chunk-major f16 | elp [128K,256K) | e2 fp32 [256K,260K)
#define WS_EHP   0
#define WS_ELP   (128*1024)
#define WS_E2    (256*1024)

// ---------------------------------------------------------------------------
// Prep: one wave per code. fp16 hi/lo split, CHUNK-MAJOR tiles:
// tile T=k>>5, chunk j=d>>3, code-in-tile c=k&31:
//   byte off = T*4096 + j*512 + c*16 + (d&7)*2
// e2 (||e||^2) stored as plain fp32 (added post-MFMA, exact).
// ---------------------------------------------------------------------------
__global__ void eprep_kernel(const float* __restrict__ emb, char* __restrict__ ws) {
    const int tid = threadIdx.x;
    const int w = tid >> 6, d = tid & 63;
    const int k = blockIdx.x * 4 + w;
    float v = emb[(size_t)k * DDIM + d];
    _Float16 h = (_Float16)v;
    _Float16 l = (_Float16)(v - (float)h);
    size_t off = (size_t)(k >> 5) * 4096 + (size_t)(d >> 3) * 512
               + (size_t)(k & 31) * 16 + (size_t)(d & 7) * 2;
    *(_Float16*)(ws + WS_EHP + off) = h;
    *(_Float16*)(ws + WS_ELP + off) = l;
    float s = v * v;
    #pragma unroll
    for (int m = 1; m < 64; m <<= 1) s += __shfl_xor(s, m, 64);
    if (d == 0) ((float*)(ws + WS_E2))[k] = s;
}

// ---------------------------------------------------------------------------
// Main: grid 512, block 256 = 4 waves; wave w owns 32 points (pgrp*128+w*32+col)
// over the FULL K=1024 (32 tiles).
//
// Round-14: BARRIER-FREE register-direct, with the prefetch-sink bug fixed.
// Evidence: all barriered variants = 40-50us regardless of occupancy (R13:
// clean 4 waves/SIMD, 31.6% occ, still 45us -> TLP conclusively null, waves
// are barrier-phase-locked); compute-only body = 22.3us (MfmaUtil 61%);
// sync-free pipeline ~30us warm. The LDS+barrier machinery costs 10-18us.
// R1/R4/R5's register-direct attempts all failed the SAME way: sched_barrier
// placed AFTER {LOADT;TILE} left loads and consumer in one region -> the
// pressure-greedy scheduler sank the prefetch to its use (VGPR stayed ~100,
// dbuf dead). Fix: LOADT(B); SB(0); TILE(A); SB(0) -- loads pinned a full
// TILE (~600cy) ahead; compiler inserts counted vmcnt(9) before first use.
// No inline-asm waits, no barriers, no LDS in the loop; waves independent.
// Single 12-MFMA chain (R13-proven) keeps ledger ~156 regs < 256 @ 2 w/EU.
// Tripwire: VGPR_Count >= 150 proves the dbuf materialized (<=110 = sunk).
//
// MFMA 32x32x16 f16 layouts (verified, absmax 0):
//   A[m][k]: m=lane&31, k=(lane>>5)*8+j ; B same with n=lane&31 ;
//   C/D: col=lane&31, row=(r&3)+8*(r>>2)+4*(lane>>5)
// ---------------------------------------------------------------------------
#define MFMA(A,B,C) __builtin_amdgcn_mfma_f32_32x32x16_f16(A,B,C,0,0,0)

__global__ __launch_bounds__(256, 2) void vq_kernel(
    const float* __restrict__ z,
    const char* __restrict__ ws_c,
    const float* __restrict__ emb,
    float* __restrict__ out)
{
    const int tid  = threadIdx.x;
    const int lane = tid & 63;
    const int w    = __builtin_amdgcn_readfirstlane(tid >> 6);
    const int col  = lane & 31;
    const int sel8 = lane >> 5;
    const int pgrp = blockIdx.x;

    __shared__ int s_final[128];

    // ---- A fragments: a = -2 z[pt], hi/lo fp16 ----
    const int pt = pgrp * 128 + w * 32 + col;
    half8 ah[4], al[4];
    {
        const float* zrow = z + (size_t)pt * DDIM + sel8 * 8;
        #pragma unroll
        for (int ks = 0; ks < 4; ++ks) {
            float4 u0 = *(const float4*)(zrow + ks * 16);
            float4 u1 = *(const float4*)(zrow + ks * 16 + 4);
            float tv[8] = {u0.x, u0.y, u0.z, u0.w, u1.x, u1.y, u1.z, u1.w};
            #pragma unroll
            for (int j = 0; j < 8; ++j) {
                float a = -2.0f * tv[j];
                _Float16 hh = (_Float16)a;
                ah[ks][j] = hh;
                al[ks][j] = (_Float16)(a - (float)hh);
            }
        }
    }

    const floatx16 zeroC = {};
    float best[16];
    int   bt[16];
    #pragma unroll
    for (int r = 0; r < 16; ++r) { best[r] = 3.4e38f; bt[r] = 0; }

    // Per-lane fragment base inside a tile (chunk-major layout):
    // each wave-load is 1KB contiguous (64 lanes x 16B), L2/L3-resident.
    const int myoff = sel8 * 512 + col * 16;
    const char*  ebase = ws_c + myoff;                 // + t*4096 + ks*1024
    const float* e2p   = (const float*)(ws_c + WS_E2); // fp32 ||e||^2

#define LOADT(BH, BL, E2, T) do {                                        \
    const char* _b = ebase + (size_t)(T) * 4096;                         \
    BH[0] = *(const half8*)(_b);                                         \
    BH[1] = *(const half8*)(_b + 1024);                                  \
    BH[2] = *(const half8*)(_b + 2048);                                  \
    BH[3] = *(const half8*)(_b + 3072);                                  \
    BL[0] = *(const half8*)(_b + WS_ELP);                                \
    BL[1] = *(const half8*)(_b + WS_ELP + 1024);                         \
    BL[2] = *(const half8*)(_b + WS_ELP + 2048);                         \
    BL[3] = *(const half8*)(_b + WS_ELP + 3072);                         \
    E2 = e2p[(T) * 32 + col];                                            \
} while (0)

// single 12-deep chain (R13-proven); argmin: add, cmp, 2 cndmask per row
#define TILE(T, BH, BL, E2) do {                                         \
    __builtin_amdgcn_s_setprio(1);                                       \
    floatx16 acc = MFMA(ah[0], BH[0], zeroC);                            \
    acc = MFMA(ah[1], BH[1], acc);                                       \
    acc = MFMA(ah[2], BH[2], acc);                                       \
    acc = MFMA(ah[3], BH[3], acc);                                       \
    acc = MFMA(ah[0], BL[0], acc);                                       \
    acc = MFMA(ah[1], BL[1], acc);                                       \
    acc = MFMA(ah[2], BL[2], acc);                                       \
    acc = MFMA(ah[3], BL[3], acc);                                       \
    acc = MFMA(al[0], BH[0], acc);                                       \
    acc = MFMA(al[1], BH[1], acc);                                       \
    acc = MFMA(al[2], BH[2], acc);                                       \
    acc = MFMA(al[3], BH[3], acc);                                       \
    __builtin_amdgcn_s_setprio(0);                                       \
    _Pragma("unroll")                                                    \
    for (int r = 0; r < 16; ++r) {                                       \
        float d = acc[r] + (E2);                                         \
        bool c = d < best[r];          /* strict <: earliest tile wins */ \
        best[r] = c ? d   : best[r];                                     \
        bt[r]   = c ? (T) : bt[r];                                       \
    }                                                                    \
} while (0)

    // Named regsets A/B (rule #20: no runtime-indexed register arrays).
    half8 bhA[4], blA[4], bhB[4], blB[4];
    float e2A, e2B;

    LOADT(bhA, blA, e2A, 0);
    __builtin_amdgcn_sched_barrier(0);

    #pragma unroll 1
    for (int t = 0; t < 32; t += 2) {
        // loads in their OWN region, fenced BEFORE the compute region:
        // scheduler cannot sink them to their use (R1/R4/R5 failure mode).
        LOADT(bhB, blB, e2B, t + 1);
        __builtin_amdgcn_sched_barrier(0);
        TILE(t, bhA, blA, e2A);
        __builtin_amdgcn_sched_barrier(0);

        LOADT(bhA, blA, e2A, (t + 2) & 31);   // wrap: harmless reload at end
        __builtin_amdgcn_sched_barrier(0);
        TILE(t + 1, bhB, blB, e2B);
        __builtin_amdgcn_sched_barrier(0);
    }
#undef LOADT
#undef TILE

    // materialize codes; butterfly argmin across the 32 columns
    int code[16];
    #pragma unroll
    for (int r = 0; r < 16; ++r) code[r] = bt[r] * 32 + col;
    #pragma unroll
    for (int m = 1; m < 32; m <<= 1) {
        #pragma unroll
        for (int r = 0; r < 16; ++r) {
            float ov = __shfl_xor(best[r], m, 64);
            int   oc = __shfl_xor(code[r], m, 64);
            bool c = (ov < best[r]) || (ov == best[r] && oc < code[r]);
            best[r] = c ? ov : best[r];
            code[r] = c ? oc : code[r];
        }
    }
    if (col == 0) {   // lanes 0 and 32: 16 rows each
        #pragma unroll
        for (int r = 0; r < 16; ++r) {
            int row = (r & 3) + 8 * (r >> 2) + 4 * sel8;
            s_final[w * 32 + row] = code[r];
        }
    }
    __syncthreads();

    // indices (coalesced) + quantized gather: 128 pts x 16 float4
    if (tid < 128)
        out[QOUT_ELEMS + (size_t)pgrp * 128 + tid] = (float)s_final[tid];
    float4* outq = (float4*)out;
    const float4* emb4 = (const float4*)emb;
    #pragma unroll
    for (int it = 0; it < 8; ++it) {
        int f  = it * 256 + tid;
        int p  = f >> 4;
        int d4 = f & 15;
        int ks = s_final[p];
        outq[((size_t)pgrp * 128 + p) * (DDIM / 4) + d4] =
            emb4[(size_t)ks * (DDIM / 4) + d4];
    }
}

extern "C" void kernel_launch(void* const* d_in, const int* in_sizes, int n_in,
                              void* d_out, int out_size, void* d_ws, size_t ws_size,
                              hipStream_t stream) {
    const float* z   = (const float*)d_in[0];
    const float* emb = (const float*)d_in[1];
    float* out = (float*)d_out;
    char* ws = (char*)d_ws;

    eprep_kernel<<<KCODES / 4, 256, 0, stream>>>(emb, ws);
    vq_kernel<<<NPTS / 128, 256, 0, stream>>>(z, ws, emb, out);
}